// Round 6
// baseline (469.099 us; speedup 1.0000x reference)
//
#include <hip/hip_runtime.h>

// Neurcomp / SIREN MLP inference — round 12: 32x32x16 MFMA, fully in-register,
// zero LDS.
// r11 post-mortem: barrier-alignment falsified (333->393). r8's plateau traced
// to the 16x16 D-layout's 4x4 cross-q-group transpose forcing LDS round-trips
// + a 17KB/wave buffer capping occupancy at 2 waves/SIMD.
// Fix: 32x32x16 bf16 MFMA. D: col=lane&31=point (all 32 pts of the wave),
// row=(reg&3)+8*(reg>>2)+4*(lane>>5)=feature [HW-verified m74/m101]. Derived:
// D -> next B-operand needs only a lane^32 exchange (shfl_xor(.,32), verified
// primitive in our own head code) + cndmask merge. State h kept canonically in
// B-fragment form (64 regs hi+lo bf16); s1 likewise; LDS = 0. Weights as A
// (A[m=lane&31][k=8*(lane>>5)+j] — pattern-extrapolated from the r6-verified
// 16x16 A layout; THE declared risk of this round). Term order per kk kept
// Wh*Hh, Wh*Hl, Wl*Hh (r8). Numerics delta vs r8: h reconstructed from hi+lo
// bf16 (2^-18/layer) + K=16-vs-32 accumulation association — both negligible.

typedef unsigned int u32;
typedef short s8v __attribute__((ext_vector_type(8)));   // 8 bf16 (bits)
typedef float f4v __attribute__((ext_vector_type(4)));
typedef float f16v __attribute__((ext_vector_type(16))); // 32x32 accumulator
typedef u32   u4v __attribute__((ext_vector_type(4)));

constexpr float OMEGA = 30.0f;
constexpr int HID = 128, NRES = 7, BT = 256;
constexpr int FRAG_ELEMS = 14 * 16384; // bf16 elems per hi/lo ws array (unchanged)

__device__ __forceinline__ float sin_om(float z) {
    float r = z * (OMEGA * 0.15915494309189535f);
    r = r - floorf(r);
    return __builtin_amdgcn_sinf(r);
}
__device__ __forceinline__ f16v mfma32(s8v a, s8v b, f16v c) {
    return __builtin_amdgcn_mfma_f32_32x32x16_bf16(a, b, c, 0, 0, 0);
}
__device__ __forceinline__ u32 fu(float f) { return __builtin_bit_cast(u32, f); }
__device__ __forceinline__ float uf(u32 b) { return __builtin_bit_cast(float, b); }
__device__ __forceinline__ float andf(float f) { return uf(fu(f) & 0xffff0000u); }
// pack: low short = hi16(a), high short = hi16(b)  (same convention as r8's PK8)
__device__ __forceinline__ u32 pkhi(float a, float b) {
    return __builtin_amdgcn_perm(fu(b), fu(a), 0x07060302u);
}
__device__ __forceinline__ u32 sx32(u32 v) { return (u32)__shfl_xor((int)v, 32); }

// ---- B-unit assembly from 4 own hi-packs + 4 own lo-packs (unit = (ft,sub)).
// Verified mapping: dest hi=0 lane: d0,d1=own p0,p1; d2,d3=partner p0,p1.
//                   dest hi=1 lane: d0,d1=partner p2,p3; d2,d3=own p2,p3.
#define BFP4(p0_,p1_,p2_,p3_, q0_,q1_,q2_,q3_, BH_, BL_) { \
    u32 wh0_ = sx32(hib ? (p0_) : (p2_)), wh1_ = sx32(hib ? (p1_) : (p3_)); \
    u32 wl0_ = sx32(hib ? (q0_) : (q2_)), wl1_ = sx32(hib ? (q1_) : (q3_)); \
    BH_.x = hib ? wh0_ : (p0_); BH_.y = hib ? wh1_ : (p1_); \
    BH_.z = hib ? (p2_) : wh0_; BH_.w = hib ? (p3_) : wh1_; \
    BL_.x = hib ? wl0_ : (q0_); BL_.y = hib ? wl1_ : (q1_); \
    BL_.z = hib ? (q2_) : wl0_; BL_.w = hib ? (q3_) : wl1_; }

// B-unit from 8 raw f32 values (rows r=8sub..8sub+7 of a tile): split + pack + exchange
#define BBUILD8(v0,v1,v2,v3,v4,v5,v6,v7, BH_, BL_) { \
    u32 p0_ = pkhi(v0,v1), p1_ = pkhi(v2,v3), p2_ = pkhi(v4,v5), p3_ = pkhi(v6,v7); \
    float l0_ = (v0)-andf(v0), l1_ = (v1)-andf(v1), l2_ = (v2)-andf(v2), l3_ = (v3)-andf(v3); \
    float l4_ = (v4)-andf(v4), l5_ = (v5)-andf(v5), l6_ = (v6)-andf(v6), l7_ = (v7)-andf(v7); \
    u32 q0_ = pkhi(l0_,l1_), q1_ = pkhi(l2_,l3_), q2_ = pkhi(l4_,l5_), q3_ = pkhi(l6_,l7_); \
    BFP4(p0_,p1_,p2_,p3_, q0_,q1_,q2_,q3_, BH_, BL_) }

// extract OWN packs (j..j+3 of a unit) back out of a B-unit (inverse exchange)
#define XTR(B_, O0,O1,O2,O3) { \
    u32 r0_ = sx32(B_.x), r1_ = sx32(B_.y), r2_ = sx32(B_.z), r3_ = sx32(B_.w); \
    O0 = hib ? r2_ : B_.x; O1 = hib ? r3_ : B_.y; \
    O2 = hib ? B_.z : r0_; O3 = hib ? B_.w : r1_; }

// unpack one hi-dword + lo-dword pair -> two f32 values (a=even row, b=odd row)
#define UNP(hd_, ld_, a_, b_) { \
    a_ = uf((hd_) << 16) + uf((ld_) << 16); \
    b_ = uf((hd_) & 0xffff0000u) + uf((ld_) & 0xffff0000u); }

// ---- 24 MFMAs of one output tile: A = weight frags, B = activation units.
// Term order per kk: Wh*Hh, Wh*Hl, Wl*Hh (matches r8).
#define MMK(kk, BP, C_) { \
    s8v ah_ = __builtin_bit_cast(s8v, whi[fb_ + kk*64]); \
    s8v al_ = __builtin_bit_cast(s8v, wlo[fb_ + kk*64]); \
    C_ = mfma32(ah_, __builtin_bit_cast(s8v, BP##H##kk), C_); \
    C_ = mfma32(ah_, __builtin_bit_cast(s8v, BP##L##kk), C_); \
    C_ = mfma32(al_, __builtin_bit_cast(s8v, BP##H##kk), C_); }
#define MMALL(BP, C_) MMK(0,BP,C_) MMK(1,BP,C_) MMK(2,BP,C_) MMK(3,BP,C_) \
                      MMK(4,BP,C_) MMK(5,BP,C_) MMK(6,BP,C_) MMK(7,BP,C_)

// acc init: C[r] = bias[32mt + (r&3)+8*(r>>2)+4*hi]
#define BIAS16(BIASP, mt, C_) { \
    f4v b0_ = *(const f4v*)((BIASP) + 32*mt +  0 + hof); \
    f4v b1_ = *(const f4v*)((BIASP) + 32*mt +  8 + hof); \
    f4v b2_ = *(const f4v*)((BIASP) + 32*mt + 16 + hof); \
    f4v b3_ = *(const f4v*)((BIASP) + 32*mt + 24 + hof); \
    C_[0]=b0_.x;  C_[1]=b0_.y;  C_[2]=b0_.z;  C_[3]=b0_.w; \
    C_[4]=b1_.x;  C_[5]=b1_.y;  C_[6]=b1_.z;  C_[7]=b1_.w; \
    C_[8]=b2_.x;  C_[9]=b2_.y;  C_[10]=b2_.z; C_[11]=b2_.w; \
    C_[12]=b3_.x; C_[13]=b3_.y; C_[14]=b3_.z; C_[15]=b3_.w; }

// mm1 tile mt: compute s1 = sin(W1*h + b1), pack, and build B-units U0,U1 directly
#define MM1T(mt, U0, U1) { \
    f16v C; BIAS16(B1l, mt, C) \
    const int fb_ = wb1 + mt*512 + lane; \
    MMALL(A, C) \
    float s0_ = sin_om(C[0]),  s1_ = sin_om(C[1]),  s2_ = sin_om(C[2]),  s3_ = sin_om(C[3]); \
    float s4_ = sin_om(C[4]),  s5_ = sin_om(C[5]),  s6_ = sin_om(C[6]),  s7_ = sin_om(C[7]); \
    float s8_ = sin_om(C[8]),  s9_ = sin_om(C[9]),  sA_ = sin_om(C[10]), sB_ = sin_om(C[11]); \
    float sC_ = sin_om(C[12]), sD_ = sin_om(C[13]), sE_ = sin_om(C[14]), sF_ = sin_om(C[15]); \
    BBUILD8(s0_,s1_,s2_,s3_,s4_,s5_,s6_,s7_, SH##U0, SL##U0) \
    BBUILD8(s8_,s9_,sA_,sB_,sC_,sD_,sE_,sF_, SH##U1, SL##U1) }

// mm2 tile mt: s2 = sin(W2*s1 + b2); epilogue h_new = h + s2, rebuilt into state
#define MM2T(mt, U0, U1) { \
    f16v C; BIAS16(B2l, mt, C) \
    const int fb_ = wb2 + mt*512 + lane; \
    MMALL(S, C) \
    u32 oh0_,oh1_,oh2_,oh3_,oh4_,oh5_,oh6_,oh7_; \
    u32 ol0_,ol1_,ol2_,ol3_,ol4_,ol5_,ol6_,ol7_; \
    XTR(AH##U0, oh0_,oh1_,oh2_,oh3_) XTR(AL##U0, ol0_,ol1_,ol2_,ol3_) \
    XTR(AH##U1, oh4_,oh5_,oh6_,oh7_) XTR(AL##U1, ol4_,ol5_,ol6_,ol7_) \
    float a0_,a1_,a2_,a3_,a4_,a5_,a6_,a7_,a8_,a9_,aA_,aB_,aC_,aD_,aE_,aF_; \
    UNP(oh0_,ol0_,a0_,a1_) UNP(oh1_,ol1_,a2_,a3_) UNP(oh2_,ol2_,a4_,a5_) UNP(oh3_,ol3_,a6_,a7_) \
    UNP(oh4_,ol4_,a8_,a9_) UNP(oh5_,ol5_,aA_,aB_) UNP(oh6_,ol6_,aC_,aD_) UNP(oh7_,ol7_,aE_,aF_) \
    float h0_ = a0_ + sin_om(C[0]),  h1_ = a1_ + sin_om(C[1]); \
    float h2_ = a2_ + sin_om(C[2]),  h3_ = a3_ + sin_om(C[3]); \
    float h4_ = a4_ + sin_om(C[4]),  h5_ = a5_ + sin_om(C[5]); \
    float h6_ = a6_ + sin_om(C[6]),  h7_ = a7_ + sin_om(C[7]); \
    float h8_ = a8_ + sin_om(C[8]),  h9_ = a9_ + sin_om(C[9]); \
    float hA_ = aA_ + sin_om(C[10]), hB_ = aB_ + sin_om(C[11]); \
    float hC_ = aC_ + sin_om(C[12]), hD_ = aD_ + sin_om(C[13]); \
    float hE_ = aE_ + sin_om(C[14]), hF_ = aF_ + sin_om(C[15]); \
    BBUILD8(h0_,h1_,h2_,h3_,h4_,h5_,h6_,h7_, AH##U0, AL##U0) \
    BBUILD8(h8_,h9_,hA_,hB_,hC_,hD_,hE_,hF_, AH##U1, AL##U1) }

// first layer: 4 consecutive features f0..f0+3 per (ft,g); f0 = 32ft+8g+4hi
#define F0G(ft, g, A_, B_, Cc_, D_) { \
    const int f0_ = 32*ft + 8*g + hof; \
    f4v wa_ = *(const f4v*)(w0p + 3*f0_); \
    f4v wb_ = *(const f4v*)(w0p + 3*f0_ + 4); \
    f4v wc_ = *(const f4v*)(w0p + 3*f0_ + 8); \
    f4v bb_ = *(const f4v*)(b0p + f0_); \
    A_  = sin_om(fmaf(wa_.x, X, fmaf(wa_.y, Y, fmaf(wa_.z, Z, bb_.x)))); \
    B_  = sin_om(fmaf(wa_.w, X, fmaf(wb_.x, Y, fmaf(wb_.y, Z, bb_.y)))); \
    Cc_ = sin_om(fmaf(wb_.z, X, fmaf(wb_.w, Y, fmaf(wc_.x, Z, bb_.z)))); \
    D_  = sin_om(fmaf(wc_.y, X, fmaf(wc_.z, Y, fmaf(wc_.w, Z, bb_.w)))); }
#define F0T(ft, U0, U1) { \
    float v0_,v1_,v2_,v3_,v4_,v5_,v6_,v7_,v8_,v9_,vA_,vB_,vC_,vD_,vE_,vF_; \
    F0G(ft,0, v0_,v1_,v2_,v3_) F0G(ft,1, v4_,v5_,v6_,v7_) \
    F0G(ft,2, v8_,v9_,vA_,vB_) F0G(ft,3, vC_,vD_,vE_,vF_) \
    BBUILD8(v0_,v1_,v2_,v3_,v4_,v5_,v6_,v7_, AH##U0, AL##U0) \
    BBUILD8(v8_,v9_,vA_,vB_,vC_,vD_,vE_,vF_, AH##U1, AL##U1) }

// head tile: P += sum_r wf[32ft + row(r)] * h[row(r)]
#define HDT(ft, U0, U1) { \
    u32 oh0_,oh1_,oh2_,oh3_,oh4_,oh5_,oh6_,oh7_; \
    u32 ol0_,ol1_,ol2_,ol3_,ol4_,ol5_,ol6_,ol7_; \
    XTR(AH##U0, oh0_,oh1_,oh2_,oh3_) XTR(AL##U0, ol0_,ol1_,ol2_,ol3_) \
    XTR(AH##U1, oh4_,oh5_,oh6_,oh7_) XTR(AL##U1, ol4_,ol5_,ol6_,ol7_) \
    float a0_,a1_,a2_,a3_,a4_,a5_,a6_,a7_,a8_,a9_,aA_,aB_,aC_,aD_,aE_,aF_; \
    UNP(oh0_,ol0_,a0_,a1_) UNP(oh1_,ol1_,a2_,a3_) UNP(oh2_,ol2_,a4_,a5_) UNP(oh3_,ol3_,a6_,a7_) \
    UNP(oh4_,ol4_,a8_,a9_) UNP(oh5_,ol5_,aA_,aB_) UNP(oh6_,ol6_,aC_,aD_) UNP(oh7_,ol7_,aE_,aF_) \
    f4v w0_ = *(const f4v*)(wfp + 32*ft +  0 + hof); \
    f4v w1_ = *(const f4v*)(wfp + 32*ft +  8 + hof); \
    f4v w2_ = *(const f4v*)(wfp + 32*ft + 16 + hof); \
    f4v w3_ = *(const f4v*)(wfp + 32*ft + 24 + hof); \
    P = fmaf(w0_.x,a0_, fmaf(w0_.y,a1_, fmaf(w0_.z,a2_, fmaf(w0_.w,a3_, P)))); \
    P = fmaf(w1_.x,a4_, fmaf(w1_.y,a5_, fmaf(w1_.z,a6_, fmaf(w1_.w,a7_, P)))); \
    P = fmaf(w2_.x,a8_, fmaf(w2_.y,a9_, fmaf(w2_.z,aA_, fmaf(w2_.w,aB_, P)))); \
    P = fmaf(w3_.x,aC_, fmaf(w3_.y,aD_, fmaf(w3_.z,aE_, fmaf(w3_.w,aF_, P)))); }

// ---- weight prep: fp32 W -> hi/lo bf16 A-frags for 32x32x16 in d_ws.
// A[m=lane&31][k=8*(lane>>5)+j] per (L, mt, kk); elem (L,mt,kk,lane,j) at
// offset 8*(((L*4+mt)*8+kk)*64 + lane) + j.
__global__ void prep_kernel(const float* __restrict__ rw1,
                            const float* __restrict__ rw2,
                            unsigned short* __restrict__ wsHi,
                            unsigned short* __restrict__ wsLo) {
    int id = blockIdx.x * 256 + threadIdx.x;      // 0 .. 28671
    int lane = id & 63, kk = (id >> 6) & 7, mt = (id >> 9) & 3, L = id >> 11;
    int i = L >> 1;
    bool isW1 = ((L & 1) == 0);
    const float* W = (isW1 ? rw1 : rw2) + i * HID * HID;
    float sc = (isW1 && i > 0) ? 0.5f : 1.0f;     // fold wgt1 (ave_first)
    int n = 32 * mt + (lane & 31);                 // output feature (A's m)
    int k0 = 16 * kk + 8 * (lane >> 5);            // input feature base (A's k)
    const float* src = W + n * HID + k0;
    int off = id * 8;
    for (int j = 0; j < 8; ++j) {
        float w = src[j] * sc;
        u32 b = __builtin_bit_cast(u32, w);
        u32 hb = b & 0xffff0000u;
        float lo = w - __builtin_bit_cast(float, hb);
        wsHi[off + j] = (unsigned short)(b >> 16);
        wsLo[off + j] = (unsigned short)(__builtin_bit_cast(u32, lo) >> 16);
    }
}

__global__ void __launch_bounds__(BT)
__attribute__((amdgpu_waves_per_eu(2, 2)))
siren_mfma(const float* __restrict__ x,
           const float* __restrict__ w0p, const float* __restrict__ b0p,
           const float* __restrict__ b1p, const float* __restrict__ b2p,
           const float* __restrict__ wfp, const float* __restrict__ bfp,
           const u4v* __restrict__ whi, const u4v* __restrict__ wlo,
           float* __restrict__ out, int NP)
{
    const int tid = threadIdx.x;
    const int wv = tid >> 6, lane = tid & 63;
    const int c = lane & 31;
    const bool hib = lane >= 32;
    const int hof = hib ? 4 : 0;
    const int base_pt = blockIdx.x * 128 + wv * 32;
    const int p = base_pt + c;

    // state: h in B-fragment form, units u=0..7 (u = 2*ft + sub), hi+lo
    u4v AH0,AH1,AH2,AH3,AH4,AH5,AH6,AH7, AL0,AL1,AL2,AL3,AL4,AL5,AL6,AL7;
    // s1 B-fragments (rebuilt every layer)
    u4v SH0,SH1,SH2,SH3,SH4,SH5,SH6,SH7, SL0,SL1,SL2,SL3,SL4,SL5,SL6,SL7;

    // ---- first SineLayer -> state
    {
        const int ix = p < NP ? p : NP - 1;
        const float X = x[3*ix], Y = x[3*ix+1], Z = x[3*ix+2];
        F0T(0, 0, 1) F0T(1, 2, 3) F0T(2, 4, 5) F0T(3, 6, 7)
    }

    // ---- residual sine layers
    for (int i = 0; i < NRES; ++i) {
        const int wb1 = (2*i) * 2048, wb2 = (2*i+1) * 2048;   // u4v index base
        const float* __restrict__ B1l = b1p + i * HID;
        const float* __restrict__ B2l = b2p + i * HID;
        MM1T(0, 0, 1) MM1T(1, 2, 3) MM1T(2, 4, 5) MM1T(3, 6, 7)
        MM2T(0, 0, 1) MM2T(1, 2, 3) MM2T(2, 4, 5) MM2T(3, 6, 7)
    }

    // ---- final linear head (0.5 = last-layer wgt2 folded here)
    float P = 0.f;
    HDT(0, 0, 1) HDT(1, 2, 3) HDT(2, 4, 5) HDT(3, 6, 7)
    P += __shfl_xor(P, 32);
    if (!hib && p < NP) out[p] = fmaf(P, 0.5f, bfp[0]);
}

extern "C" void kernel_launch(void* const* d_in, const int* in_sizes, int n_in,
                              void* d_out, int out_size, void* d_ws, size_t ws_size,
                              hipStream_t stream) {
    const float* x   = (const float*)d_in[0];
    const float* w0  = (const float*)d_in[1];
    const float* b0  = (const float*)d_in[2];
    const float* rw1 = (const float*)d_in[3];
    const float* rb1 = (const float*)d_in[4];
    const float* rw2 = (const float*)d_in[5];
    const float* rb2 = (const float*)d_in[6];
    const float* wf  = (const float*)d_in[7];
    const float* bf  = (const float*)d_in[8];
    float* out = (float*)d_out;

    unsigned short* wsHi = (unsigned short*)d_ws;          // needs 917504 B
    unsigned short* wsLo = wsHi + FRAG_ELEMS;

    const int n = in_sizes[0] / 3;                          // 200000
    prep_kernel<<<112, 256, 0, stream>>>(rw1, rw2, wsHi, wsLo);
    const int grid = (n + 127) / 128;
    siren_mfma<<<grid, BT, 0, stream>>>(x, w0, b0, rb1, rb2, wf, bf,
                                        (const u4v*)wsHi, (const u4v*)wsLo,
                                        out, n);
}

// Round 7
// 447.280 us; speedup vs baseline: 1.0488x; 1.0488x over previous
//
#include <hip/hip_runtime.h>

// Neurcomp / SIREN MLP inference — round 13: r12 (32x32 MFMA, zero LDS) +
// sched_barrier load-hoist fences + launch_bounds(BT,2).
// r12 post-mortem: layouts correct (passed, absmax identical), but VGPR pinned
// at 128 with 103MB scratch WRITE_SIZE (~64 regs spilled). Cause: persistent
// state (64 h-frags + 64 s1-frags) PLUS the scheduler hoisting all 4 tiles'
// weight loads (up to 256 regs in flight) -> demand ~300 over the 128 cap.
// Fix: (1) __builtin_amdgcn_sched_barrier(0x0F) between tiles — compute may
// cross, VMEM may not -> in-flight loads <= 16 u4v; (2) request the 2-wave
// 256-reg budget via the documented __launch_bounds__(256, 2) form (r9/r10/r12
// showed amdgpu_waves_per_eu never delivered >128).
// All numerics byte-identical to the r12 kernel (which passed).
// Layouts: D col=lane&31=point, row=(reg&3)+8*(reg>>2)+4*(lane>>5) [m74/m101];
// A[m=lane&31][k=8*(lane>>5)+j], B symmetric (r12-verified on HW).

typedef unsigned int u32;
typedef short s8v __attribute__((ext_vector_type(8)));   // 8 bf16 (bits)
typedef float f4v __attribute__((ext_vector_type(4)));
typedef float f16v __attribute__((ext_vector_type(16))); // 32x32 accumulator
typedef u32   u4v __attribute__((ext_vector_type(4)));

constexpr float OMEGA = 30.0f;
constexpr int HID = 128, NRES = 7, BT = 256;
constexpr int FRAG_ELEMS = 14 * 16384; // bf16 elems per hi/lo ws array

__device__ __forceinline__ float sin_om(float z) {
    float r = z * (OMEGA * 0.15915494309189535f);
    r = r - floorf(r);
    return __builtin_amdgcn_sinf(r);
}
__device__ __forceinline__ f16v mfma32(s8v a, s8v b, f16v c) {
    return __builtin_amdgcn_mfma_f32_32x32x16_bf16(a, b, c, 0, 0, 0);
}
__device__ __forceinline__ u32 fu(float f) { return __builtin_bit_cast(u32, f); }
__device__ __forceinline__ float uf(u32 b) { return __builtin_bit_cast(float, b); }
__device__ __forceinline__ float andf(float f) { return uf(fu(f) & 0xffff0000u); }
// pack: low short = hi16(a), high short = hi16(b)
__device__ __forceinline__ u32 pkhi(float a, float b) {
    return __builtin_amdgcn_perm(fu(b), fu(a), 0x07060302u);
}
__device__ __forceinline__ u32 sx32(u32 v) { return (u32)__shfl_xor((int)v, 32); }

// sched fence: ALU/VALU/SALU/MFMA may cross (0x1|0x2|0x4|0x8), VMEM/DS may not.
#define SB __builtin_amdgcn_sched_barrier(0x0F);

// ---- B-unit assembly from 4 own hi-packs + 4 own lo-packs.
#define BFP4(p0_,p1_,p2_,p3_, q0_,q1_,q2_,q3_, BH_, BL_) { \
    u32 wh0_ = sx32(hib ? (p0_) : (p2_)), wh1_ = sx32(hib ? (p1_) : (p3_)); \
    u32 wl0_ = sx32(hib ? (q0_) : (q2_)), wl1_ = sx32(hib ? (q1_) : (q3_)); \
    BH_.x = hib ? wh0_ : (p0_); BH_.y = hib ? wh1_ : (p1_); \
    BH_.z = hib ? (p2_) : wh0_; BH_.w = hib ? (p3_) : wh1_; \
    BL_.x = hib ? wl0_ : (q0_); BL_.y = hib ? wl1_ : (q1_); \
    BL_.z = hib ? (q2_) : wl0_; BL_.w = hib ? (q3_) : wl1_; }

// B-unit from 8 raw f32 values (rows r=8sub..8sub+7): split + pack + exchange
#define BBUILD8(v0,v1,v2,v3,v4,v5,v6,v7, BH_, BL_) { \
    u32 p0_ = pkhi(v0,v1), p1_ = pkhi(v2,v3), p2_ = pkhi(v4,v5), p3_ = pkhi(v6,v7); \
    float l0_ = (v0)-andf(v0), l1_ = (v1)-andf(v1), l2_ = (v2)-andf(v2), l3_ = (v3)-andf(v3); \
    float l4_ = (v4)-andf(v4), l5_ = (v5)-andf(v5), l6_ = (v6)-andf(v6), l7_ = (v7)-andf(v7); \
    u32 q0_ = pkhi(l0_,l1_), q1_ = pkhi(l2_,l3_), q2_ = pkhi(l4_,l5_), q3_ = pkhi(l6_,l7_); \
    BFP4(p0_,p1_,p2_,p3_, q0_,q1_,q2_,q3_, BH_, BL_) }

// extract OWN packs back out of a B-unit (inverse exchange)
#define XTR(B_, O0,O1,O2,O3) { \
    u32 r0_ = sx32(B_.x), r1_ = sx32(B_.y), r2_ = sx32(B_.z), r3_ = sx32(B_.w); \
    O0 = hib ? r2_ : B_.x; O1 = hib ? r3_ : B_.y; \
    O2 = hib ? B_.z : r0_; O3 = hib ? B_.w : r1_; }

// unpack one hi-dword + lo-dword pair -> two f32 values
#define UNP(hd_, ld_, a_, b_) { \
    a_ = uf((hd_) << 16) + uf((ld_) << 16); \
    b_ = uf((hd_) & 0xffff0000u) + uf((ld_) & 0xffff0000u); }

// ---- 24 MFMAs of one output tile. Term order per kk: Wh*Hh, Wh*Hl, Wl*Hh.
#define MMK(kk, BP, C_) { \
    s8v ah_ = __builtin_bit_cast(s8v, whi[fb_ + kk*64]); \
    s8v al_ = __builtin_bit_cast(s8v, wlo[fb_ + kk*64]); \
    C_ = mfma32(ah_, __builtin_bit_cast(s8v, BP##H##kk), C_); \
    C_ = mfma32(ah_, __builtin_bit_cast(s8v, BP##L##kk), C_); \
    C_ = mfma32(al_, __builtin_bit_cast(s8v, BP##H##kk), C_); }
#define MMALL(BP, C_) MMK(0,BP,C_) MMK(1,BP,C_) MMK(2,BP,C_) MMK(3,BP,C_) \
                      MMK(4,BP,C_) MMK(5,BP,C_) MMK(6,BP,C_) MMK(7,BP,C_)

// acc init: C[r] = bias[32mt + (r&3)+8*(r>>2)+4*hi]
#define BIAS16(BIASP, mt, C_) { \
    f4v b0_ = *(const f4v*)((BIASP) + 32*mt +  0 + hof); \
    f4v b1_ = *(const f4v*)((BIASP) + 32*mt +  8 + hof); \
    f4v b2_ = *(const f4v*)((BIASP) + 32*mt + 16 + hof); \
    f4v b3_ = *(const f4v*)((BIASP) + 32*mt + 24 + hof); \
    C_[0]=b0_.x;  C_[1]=b0_.y;  C_[2]=b0_.z;  C_[3]=b0_.w; \
    C_[4]=b1_.x;  C_[5]=b1_.y;  C_[6]=b1_.z;  C_[7]=b1_.w; \
    C_[8]=b2_.x;  C_[9]=b2_.y;  C_[10]=b2_.z; C_[11]=b2_.w; \
    C_[12]=b3_.x; C_[13]=b3_.y; C_[14]=b3_.z; C_[15]=b3_.w; }

// mm1 tile mt: s1 = sin(W1*h + b1) -> B-units U0,U1
#define MM1T(mt, U0, U1) { \
    f16v C; BIAS16(B1l, mt, C) \
    const int fb_ = wb1 + mt*512 + lane; \
    MMALL(A, C) \
    float s0_ = sin_om(C[0]),  s1_ = sin_om(C[1]),  s2_ = sin_om(C[2]),  s3_ = sin_om(C[3]); \
    float s4_ = sin_om(C[4]),  s5_ = sin_om(C[5]),  s6_ = sin_om(C[6]),  s7_ = sin_om(C[7]); \
    float s8_ = sin_om(C[8]),  s9_ = sin_om(C[9]),  sA_ = sin_om(C[10]), sB_ = sin_om(C[11]); \
    float sC_ = sin_om(C[12]), sD_ = sin_om(C[13]), sE_ = sin_om(C[14]), sF_ = sin_om(C[15]); \
    BBUILD8(s0_,s1_,s2_,s3_,s4_,s5_,s6_,s7_, SH##U0, SL##U0) \
    BBUILD8(s8_,s9_,sA_,sB_,sC_,sD_,sE_,sF_, SH##U1, SL##U1) }

// mm2 tile mt: s2 = sin(W2*s1 + b2); h_new = h + s2, rebuilt into state
#define MM2T(mt, U0, U1) { \
    f16v C; BIAS16(B2l, mt, C) \
    const int fb_ = wb2 + mt*512 + lane; \
    MMALL(S, C) \
    u32 oh0_,oh1_,oh2_,oh3_,oh4_,oh5_,oh6_,oh7_; \
    u32 ol0_,ol1_,ol2_,ol3_,ol4_,ol5_,ol6_,ol7_; \
    XTR(AH##U0, oh0_,oh1_,oh2_,oh3_) XTR(AL##U0, ol0_,ol1_,ol2_,ol3_) \
    XTR(AH##U1, oh4_,oh5_,oh6_,oh7_) XTR(AL##U1, ol4_,ol5_,ol6_,ol7_) \
    float a0_,a1_,a2_,a3_,a4_,a5_,a6_,a7_,a8_,a9_,aA_,aB_,aC_,aD_,aE_,aF_; \
    UNP(oh0_,ol0_,a0_,a1_) UNP(oh1_,ol1_,a2_,a3_) UNP(oh2_,ol2_,a4_,a5_) UNP(oh3_,ol3_,a6_,a7_) \
    UNP(oh4_,ol4_,a8_,a9_) UNP(oh5_,ol5_,aA_,aB_) UNP(oh6_,ol6_,aC_,aD_) UNP(oh7_,ol7_,aE_,aF_) \
    float h0_ = a0_ + sin_om(C[0]),  h1_ = a1_ + sin_om(C[1]); \
    float h2_ = a2_ + sin_om(C[2]),  h3_ = a3_ + sin_om(C[3]); \
    float h4_ = a4_ + sin_om(C[4]),  h5_ = a5_ + sin_om(C[5]); \
    float h6_ = a6_ + sin_om(C[6]),  h7_ = a7_ + sin_om(C[7]); \
    float h8_ = a8_ + sin_om(C[8]),  h9_ = a9_ + sin_om(C[9]); \
    float hA_ = aA_ + sin_om(C[10]), hB_ = aB_ + sin_om(C[11]); \
    float hC_ = aC_ + sin_om(C[12]), hD_ = aD_ + sin_om(C[13]); \
    float hE_ = aE_ + sin_om(C[14]), hF_ = aF_ + sin_om(C[15]); \
    BBUILD8(h0_,h1_,h2_,h3_,h4_,h5_,h6_,h7_, AH##U0, AL##U0) \
    BBUILD8(h8_,h9_,hA_,hB_,hC_,hD_,hE_,hF_, AH##U1, AL##U1) }

// first layer: 4 consecutive features f0..f0+3 per (ft,g); f0 = 32ft+8g+4hi
#define F0G(ft, g, A_, B_, Cc_, D_) { \
    const int f0_ = 32*ft + 8*g + hof; \
    f4v wa_ = *(const f4v*)(w0p + 3*f0_); \
    f4v wb_ = *(const f4v*)(w0p + 3*f0_ + 4); \
    f4v wc_ = *(const f4v*)(w0p + 3*f0_ + 8); \
    f4v bb_ = *(const f4v*)(b0p + f0_); \
    A_  = sin_om(fmaf(wa_.x, X, fmaf(wa_.y, Y, fmaf(wa_.z, Z, bb_.x)))); \
    B_  = sin_om(fmaf(wa_.w, X, fmaf(wb_.x, Y, fmaf(wb_.y, Z, bb_.y)))); \
    Cc_ = sin_om(fmaf(wb_.z, X, fmaf(wb_.w, Y, fmaf(wc_.x, Z, bb_.z)))); \
    D_  = sin_om(fmaf(wc_.y, X, fmaf(wc_.z, Y, fmaf(wc_.w, Z, bb_.w)))); }
#define F0T(ft, U0, U1) { \
    float v0_,v1_,v2_,v3_,v4_,v5_,v6_,v7_,v8_,v9_,vA_,vB_,vC_,vD_,vE_,vF_; \
    F0G(ft,0, v0_,v1_,v2_,v3_) F0G(ft,1, v4_,v5_,v6_,v7_) \
    F0G(ft,2, v8_,v9_,vA_,vB_) F0G(ft,3, vC_,vD_,vE_,vF_) \
    BBUILD8(v0_,v1_,v2_,v3_,v4_,v5_,v6_,v7_, AH##U0, AL##U0) \
    BBUILD8(v8_,v9_,vA_,vB_,vC_,vD_,vE_,vF_, AH##U1, AL##U1) }

// head tile: P += sum_r wf[32ft + row(r)] * h[row(r)]
#define HDT(ft, U0, U1) { \
    u32 oh0_,oh1_,oh2_,oh3_,oh4_,oh5_,oh6_,oh7_; \
    u32 ol0_,ol1_,ol2_,ol3_,ol4_,ol5_,ol6_,ol7_; \
    XTR(AH##U0, oh0_,oh1_,oh2_,oh3_) XTR(AL##U0, ol0_,ol1_,ol2_,ol3_) \
    XTR(AH##U1, oh4_,oh5_,oh6_,oh7_) XTR(AL##U1, ol4_,ol5_,ol6_,ol7_) \
    float a0_,a1_,a2_,a3_,a4_,a5_,a6_,a7_,a8_,a9_,aA_,aB_,aC_,aD_,aE_,aF_; \
    UNP(oh0_,ol0_,a0_,a1_) UNP(oh1_,ol1_,a2_,a3_) UNP(oh2_,ol2_,a4_,a5_) UNP(oh3_,ol3_,a6_,a7_) \
    UNP(oh4_,ol4_,a8_,a9_) UNP(oh5_,ol5_,aA_,aB_) UNP(oh6_,ol6_,aC_,aD_) UNP(oh7_,ol7_,aE_,aF_) \
    f4v w0_ = *(const f4v*)(wfp + 32*ft +  0 + hof); \
    f4v w1_ = *(const f4v*)(wfp + 32*ft +  8 + hof); \
    f4v w2_ = *(const f4v*)(wfp + 32*ft + 16 + hof); \
    f4v w3_ = *(const f4v*)(wfp + 32*ft + 24 + hof); \
    P = fmaf(w0_.x,a0_, fmaf(w0_.y,a1_, fmaf(w0_.z,a2_, fmaf(w0_.w,a3_, P)))); \
    P = fmaf(w1_.x,a4_, fmaf(w1_.y,a5_, fmaf(w1_.z,a6_, fmaf(w1_.w,a7_, P)))); \
    P = fmaf(w2_.x,a8_, fmaf(w2_.y,a9_, fmaf(w2_.z,aA_, fmaf(w2_.w,aB_, P)))); \
    P = fmaf(w3_.x,aC_, fmaf(w3_.y,aD_, fmaf(w3_.z,aE_, fmaf(w3_.w,aF_, P)))); }

// ---- weight prep: fp32 W -> hi/lo bf16 A-frags for 32x32x16 (unchanged r12).
__global__ void prep_kernel(const float* __restrict__ rw1,
                            const float* __restrict__ rw2,
                            unsigned short* __restrict__ wsHi,
                            unsigned short* __restrict__ wsLo) {
    int id = blockIdx.x * 256 + threadIdx.x;      // 0 .. 28671
    int lane = id & 63, kk = (id >> 6) & 7, mt = (id >> 9) & 3, L = id >> 11;
    int i = L >> 1;
    bool isW1 = ((L & 1) == 0);
    const float* W = (isW1 ? rw1 : rw2) + i * HID * HID;
    float sc = (isW1 && i > 0) ? 0.5f : 1.0f;     // fold wgt1 (ave_first)
    int n = 32 * mt + (lane & 31);                 // output feature (A's m)
    int k0 = 16 * kk + 8 * (lane >> 5);            // input feature base (A's k)
    const float* src = W + n * HID + k0;
    int off = id * 8;
    for (int j = 0; j < 8; ++j) {
        float w = src[j] * sc;
        u32 b = __builtin_bit_cast(u32, w);
        u32 hb = b & 0xffff0000u;
        float lo = w - __builtin_bit_cast(float, hb);
        wsHi[off + j] = (unsigned short)(b >> 16);
        wsLo[off + j] = (unsigned short)(__builtin_bit_cast(u32, lo) >> 16);
    }
}

__global__ void __launch_bounds__(BT, 2)
siren_mfma(const float* __restrict__ x,
           const float* __restrict__ w0p, const float* __restrict__ b0p,
           const float* __restrict__ b1p, const float* __restrict__ b2p,
           const float* __restrict__ wfp, const float* __restrict__ bfp,
           const u4v* __restrict__ whi, const u4v* __restrict__ wlo,
           float* __restrict__ out, int NP)
{
    const int tid = threadIdx.x;
    const int wv = tid >> 6, lane = tid & 63;
    const int c = lane & 31;
    const bool hib = lane >= 32;
    const int hof = hib ? 4 : 0;
    const int base_pt = blockIdx.x * 128 + wv * 32;
    const int p = base_pt + c;

    // state: h in B-fragment form, units u=0..7, hi+lo
    u4v AH0,AH1,AH2,AH3,AH4,AH5,AH6,AH7, AL0,AL1,AL2,AL3,AL4,AL5,AL6,AL7;
    // s1 B-fragments (rebuilt every layer)
    u4v SH0,SH1,SH2,SH3,SH4,SH5,SH6,SH7, SL0,SL1,SL2,SL3,SL4,SL5,SL6,SL7;

    // ---- first SineLayer -> state
    {
        const int ix = p < NP ? p : NP - 1;
        const float X = x[3*ix], Y = x[3*ix+1], Z = x[3*ix+2];
        F0T(0, 0, 1) F0T(1, 2, 3) F0T(2, 4, 5) F0T(3, 6, 7)
    }

    // ---- residual sine layers
    for (int i = 0; i < NRES; ++i) {
        const int wb1 = (2*i) * 2048, wb2 = (2*i+1) * 2048;   // u4v index base
        const float* __restrict__ B1l = b1p + i * HID;
        const float* __restrict__ B2l = b2p + i * HID;
        SB MM1T(0, 0, 1) SB MM1T(1, 2, 3) SB MM1T(2, 4, 5) SB MM1T(3, 6, 7)
        SB MM2T(0, 0, 1) SB MM2T(1, 2, 3) SB MM2T(2, 4, 5) SB MM2T(3, 6, 7)
    }

    // ---- final linear head (0.5 = last-layer wgt2 folded here)
    float P = 0.f;
    HDT(0, 0, 1) HDT(1, 2, 3) HDT(2, 4, 5) HDT(3, 6, 7)
    P += __shfl_xor(P, 32);
    if (!hib && p < NP) out[p] = fmaf(P, 0.5f, bfp[0]);
}

extern "C" void kernel_launch(void* const* d_in, const int* in_sizes, int n_in,
                              void* d_out, int out_size, void* d_ws, size_t ws_size,
                              hipStream_t stream) {
    const float* x   = (const float*)d_in[0];
    const float* w0  = (const float*)d_in[1];
    const float* b0  = (const float*)d_in[2];
    const float* rw1 = (const float*)d_in[3];
    const float* rb1 = (const float*)d_in[4];
    const float* rw2 = (const float*)d_in[5];
    const float* rb2 = (const float*)d_in[6];
    const float* wf  = (const float*)d_in[7];
    const float* bf  = (const float*)d_in[8];
    float* out = (float*)d_out;

    unsigned short* wsHi = (unsigned short*)d_ws;          // needs 917504 B
    unsigned short* wsLo = wsHi + FRAG_ELEMS;

    const int n = in_sizes[0] / 3;                          // 200000
    prep_kernel<<<112, 256, 0, stream>>>(rw1, rw2, wsHi, wsLo);
    const int grid = (n + 127) / 128;
    siren_mfma<<<grid, BT, 0, stream>>>(x, w0, b0, rb1, rb2, wf, bf,
                                        (const u4v*)wsHi, (const u4v*)wsLo,
                                        out, n);
}

// Round 8
// 360.769 us; speedup vs baseline: 1.3003x; 1.2398x over previous
//
#include <hip/hip_runtime.h>

// Neurcomp / SIREN MLP inference — round 14: r8 structure + explicit 1-deep
// software pipeline of weight+bias loads (ping-pong registers).
// r12/r13 post-mortem: zero-LDS 32x32 branch abandoned — ~190-reg persistent
// demand pins the allocator at the 128 split with residual spills, and its
// serial ds_bpermute chains add VALU + stall (430us vs r8's 333).
// r8 analysis: 24% stall, VGPR 108/256 — compiler keeps <=1 weight tile in
// flight, so each t-block exposes L2 latency (~200-250cy vs ~350cy compute).
// Fix: ping-pong prefetch buffers (ga*/ra*/cva vs gb*/rb*/cvb, ~68 extra regs
// -> ~180 total, no spill at the 2-wave 256 budget): prefetch t+1 before
// consuming t; mm2-t0 prefetched during mm1-t7; mm1-t0 prefetched at layer top
// (covered by the WH/RS transpose phase). No barriers (r11 regression).
// Numerics byte-identical to verified r8: same loads, same MFMA term order
// (Wh*Hh, Wh*Hl, Wl*Hh per kc), same sin_om, same epilogue.
// Layouts (learn_hip m89/m120, r6/r8-verified): A[m=lane&15][k=(lane>>4)*8+j],
// B[k=(lane>>4)*8+j][n=lane&15], D row=(lane>>4)*4+reg, col=lane&15.
// A = weights (prep layout unchanged), B = activations; D: feature row, point col.

typedef unsigned int u32;
typedef short s8v __attribute__((ext_vector_type(8)));   // 8 bf16 (bits)
typedef float f4v __attribute__((ext_vector_type(4)));
typedef u32   u4v __attribute__((ext_vector_type(4)));

constexpr float OMEGA = 30.0f;
constexpr int HID = 128, NRES = 7, BT = 256;
constexpr int WROW = 136;              // dwords per LDS row: 32 b128-blocks + 2 pad
constexpr int WAVE_LDS = 32 * WROW;    // 4352 dwords per wave (32 rows)
constexpr int FRAG_ELEMS = 14 * 16384; // bf16 elems per hi/lo ws array

__device__ __forceinline__ float sin_om(float z) {
    float r = z * (OMEGA * 0.15915494309189535f);
    r = r - floorf(r);
    return __builtin_amdgcn_sinf(r);
}
__device__ __forceinline__ f4v mfma16(s8v a, s8v b, f4v c) {
    return __builtin_amdgcn_mfma_f32_16x16x32_bf16(a, b, c, 0, 0, 0);
}
__device__ __forceinline__ u32 fu(float f) { return __builtin_bit_cast(u32, f); }
__device__ __forceinline__ float andf(float f) {
    return __builtin_bit_cast(float, __builtin_bit_cast(u32, f) & 0xffff0000u);
}
__device__ __forceinline__ s8v bc(u4v v) { return __builtin_bit_cast(s8v, v); }

// 8 fp32 (frag elem order j=0..7) -> hi s8v + lo s8v (truncation split).
// v_perm sel 0x07060302: D = {a.hi16 (top), b.hi16 (low)}.
#define PK8(e0,e1,e2,e3,e4,e5,e6,e7, FH_, FL_) { \
    u4v h_, l_; \
    h_.x = __builtin_amdgcn_perm(fu(e1), fu(e0), 0x07060302u); \
    h_.y = __builtin_amdgcn_perm(fu(e3), fu(e2), 0x07060302u); \
    h_.z = __builtin_amdgcn_perm(fu(e5), fu(e4), 0x07060302u); \
    h_.w = __builtin_amdgcn_perm(fu(e7), fu(e6), 0x07060302u); \
    float L0_ = e0 - andf(e0), L1_ = e1 - andf(e1); \
    float L2_ = e2 - andf(e2), L3_ = e3 - andf(e3); \
    float L4_ = e4 - andf(e4), L5_ = e5 - andf(e5); \
    float L6_ = e6 - andf(e6), L7_ = e7 - andf(e7); \
    l_.x = __builtin_amdgcn_perm(fu(L1_), fu(L0_), 0x07060302u); \
    l_.y = __builtin_amdgcn_perm(fu(L3_), fu(L2_), 0x07060302u); \
    l_.z = __builtin_amdgcn_perm(fu(L5_), fu(L4_), 0x07060302u); \
    l_.w = __builtin_amdgcn_perm(fu(L7_), fu(L6_), 0x07060302u); \
    FH_ = __builtin_bit_cast(s8v, h_); FL_ = __builtin_bit_cast(s8v, l_); }

// h (D-layout regs, feature 16nt+4q+reg at point-row) -> LDS, b128 swizzled.
#define WH(mt,nt) { \
    f4v hv_; hv_.x = H_##mt##_##nt##_0; hv_.y = H_##mt##_##nt##_1; \
    hv_.z = H_##mt##_##nt##_2; hv_.w = H_##mt##_##nt##_3; \
    *(f4v*)&buf[(mt ? rowbase1 : rowbase0) + ((((nt)*4 + q) ^ lnk) << 2)] = hv_; }

// LDS -> B-fragments, split-on-read.
#define RS(mt,kc) { \
    const int rb_ = mt ? rowbase1 : rowbase0; \
    f4v u_ = *(const f4v*)&buf[rb_ + ((((kc)*8 + q*2    ) ^ lnk) << 2)]; \
    f4v v_ = *(const f4v*)&buf[rb_ + ((((kc)*8 + q*2 + 1) ^ lnk) << 2)]; \
    PK8(u_.x, u_.y, u_.z, u_.w, v_.x, v_.y, v_.z, v_.w, FH##mt##kc, FL##mt##kc) }

// prefetch weight tile + bias into buffer S (S = a or b)
#define PF(S, fbv, bp) { \
    g##S##0 = whi[fbv]; g##S##1 = whi[(fbv)+64]; \
    g##S##2 = whi[(fbv)+128]; g##S##3 = whi[(fbv)+192]; \
    r##S##0 = wlo[fbv]; r##S##1 = wlo[(fbv)+64]; \
    r##S##2 = wlo[(fbv)+128]; r##S##3 = wlo[(fbv)+192]; \
    cv##S = *(const f4v*)(bp); }

// 24 MFMAs consuming buffer S. Term order per kc: Wh*Hh, Wh*Hl, Wl*Hh.
#define MMB(S) { s8v bh_, bl_; \
    bh_ = bc(g##S##0); bl_ = bc(r##S##0); \
    c0 = mfma16(bh_, FH00, c0); c0 = mfma16(bh_, FL00, c0); c0 = mfma16(bl_, FH00, c0); \
    c1 = mfma16(bh_, FH10, c1); c1 = mfma16(bh_, FL10, c1); c1 = mfma16(bl_, FH10, c1); \
    bh_ = bc(g##S##1); bl_ = bc(r##S##1); \
    c0 = mfma16(bh_, FH01, c0); c0 = mfma16(bh_, FL01, c0); c0 = mfma16(bl_, FH01, c0); \
    c1 = mfma16(bh_, FH11, c1); c1 = mfma16(bh_, FL11, c1); c1 = mfma16(bl_, FH11, c1); \
    bh_ = bc(g##S##2); bl_ = bc(r##S##2); \
    c0 = mfma16(bh_, FH02, c0); c0 = mfma16(bh_, FL02, c0); c0 = mfma16(bl_, FH02, c0); \
    c1 = mfma16(bh_, FH12, c1); c1 = mfma16(bh_, FL12, c1); c1 = mfma16(bl_, FH12, c1); \
    bh_ = bc(g##S##3); bl_ = bc(r##S##3); \
    c0 = mfma16(bh_, FH03, c0); c0 = mfma16(bh_, FL03, c0); c0 = mfma16(bl_, FH03, c0); \
    c1 = mfma16(bh_, FH13, c1); c1 = mfma16(bh_, FL13, c1); c1 = mfma16(bl_, FH13, c1); }

// mm1 step t consuming buffer S: s1 = sin(...), staged to LDS (b128, swizzled)
#define S1(t, S) { \
    f4v c0 = cv##S; f4v c1 = c0; \
    MMB(S) \
    f4v s0v, s1v; \
    s0v.x = sin_om(c0.x); s0v.y = sin_om(c0.y); \
    s0v.z = sin_om(c0.z); s0v.w = sin_om(c0.w); \
    s1v.x = sin_om(c1.x); s1v.y = sin_om(c1.y); \
    s1v.z = sin_om(c1.z); s1v.w = sin_om(c1.w); \
    const int bo_ = (((t)*4 + q) ^ lnk) << 2; \
    *(f4v*)&buf[rowbase0 + bo_] = s0v; \
    *(f4v*)&buf[rowbase1 + bo_] = s1v; }

// mm2 step t consuming buffer S: epilogue h += s2 (last-layer 0.5 in head)
#define S2(t, S) { \
    f4v c0 = cv##S; f4v c1 = c0; \
    MMB(S) \
    H_0_##t##_0 += sin_om(c0.x); H_0_##t##_1 += sin_om(c0.y); \
    H_0_##t##_2 += sin_om(c0.z); H_0_##t##_3 += sin_om(c0.w); \
    H_1_##t##_0 += sin_om(c1.x); H_1_##t##_1 += sin_om(c1.y); \
    H_1_##t##_2 += sin_om(c1.z); H_1_##t##_3 += sin_om(c1.w); }

// ---- repetition lists ----
#define LNT8(M) M(0) M(1) M(2) M(3) M(4) M(5) M(6) M(7)
#define LW16(M) M(0,0) M(0,1) M(0,2) M(0,3) M(0,4) M(0,5) M(0,6) M(0,7) \
                M(1,0) M(1,1) M(1,2) M(1,3) M(1,4) M(1,5) M(1,6) M(1,7)
#define LH64(M) \
  M(0,0,0) M(0,0,1) M(0,0,2) M(0,0,3) M(0,1,0) M(0,1,1) M(0,1,2) M(0,1,3) \
  M(0,2,0) M(0,2,1) M(0,2,2) M(0,2,3) M(0,3,0) M(0,3,1) M(0,3,2) M(0,3,3) \
  M(0,4,0) M(0,4,1) M(0,4,2) M(0,4,3) M(0,5,0) M(0,5,1) M(0,5,2) M(0,5,3) \
  M(0,6,0) M(0,6,1) M(0,6,2) M(0,6,3) M(0,7,0) M(0,7,1) M(0,7,2) M(0,7,3) \
  M(1,0,0) M(1,0,1) M(1,0,2) M(1,0,3) M(1,1,0) M(1,1,1) M(1,1,2) M(1,1,3) \
  M(1,2,0) M(1,2,1) M(1,2,2) M(1,2,3) M(1,3,0) M(1,3,1) M(1,3,2) M(1,3,3) \
  M(1,4,0) M(1,4,1) M(1,4,2) M(1,4,3) M(1,5,0) M(1,5,1) M(1,5,2) M(1,5,3) \
  M(1,6,0) M(1,6,1) M(1,6,2) M(1,6,3) M(1,7,0) M(1,7,1) M(1,7,2) M(1,7,3)

#define DH(mt,nt,reg) float H_##mt##_##nt##_##reg;

// first layer
#define F0(nt) { \
    f4v wa_ = *(const f4v*)(w0p + nt*48 + q*12); \
    f4v wb_ = *(const f4v*)(w0p + nt*48 + q*12 + 4); \
    f4v wc_ = *(const f4v*)(w0p + nt*48 + q*12 + 8); \
    f4v bb_ = *(const f4v*)(b0p + nt*16 + q4); \
    H_0_##nt##_0 = sin_om(fmaf(wa_.x, X0, fmaf(wa_.y, Y0, fmaf(wa_.z, Z0, bb_.x)))); \
    H_0_##nt##_1 = sin_om(fmaf(wa_.w, X0, fmaf(wb_.x, Y0, fmaf(wb_.y, Z0, bb_.y)))); \
    H_0_##nt##_2 = sin_om(fmaf(wb_.z, X0, fmaf(wb_.w, Y0, fmaf(wc_.x, Z0, bb_.z)))); \
    H_0_##nt##_3 = sin_om(fmaf(wc_.y, X0, fmaf(wc_.z, Y0, fmaf(wc_.w, Z0, bb_.w)))); \
    H_1_##nt##_0 = sin_om(fmaf(wa_.x, X1, fmaf(wa_.y, Y1, fmaf(wa_.z, Z1, bb_.x)))); \
    H_1_##nt##_1 = sin_om(fmaf(wa_.w, X1, fmaf(wb_.x, Y1, fmaf(wb_.y, Z1, bb_.y)))); \
    H_1_##nt##_2 = sin_om(fmaf(wb_.z, X1, fmaf(wb_.w, Y1, fmaf(wc_.x, Z1, bb_.z)))); \
    H_1_##nt##_3 = sin_om(fmaf(wc_.y, X1, fmaf(wc_.z, Y1, fmaf(wc_.w, Z1, bb_.w)))); }

// final head partials
#define HF(nt) { f4v wf_ = *(const f4v*)(wfp + nt*16 + q4); \
    P0 = fmaf(wf_.x, H_0_##nt##_0, fmaf(wf_.y, H_0_##nt##_1, \
         fmaf(wf_.z, H_0_##nt##_2, fmaf(wf_.w, H_0_##nt##_3, P0)))); \
    P1 = fmaf(wf_.x, H_1_##nt##_0, fmaf(wf_.y, H_1_##nt##_1, \
         fmaf(wf_.z, H_1_##nt##_2, fmaf(wf_.w, H_1_##nt##_3, P1)))); }

// ---- weight prep: fp32 W -> hi/lo bf16 fragments in d_ws (UNCHANGED r8) ----
__global__ void prep_kernel(const float* __restrict__ rw1,
                            const float* __restrict__ rw2,
                            unsigned short* __restrict__ wsHi,
                            unsigned short* __restrict__ wsLo) {
    int id = blockIdx.x * 256 + threadIdx.x;      // 0 .. 28671
    int lane = id & 63, kc = (id >> 6) & 3, t = (id >> 8) & 7, L = id >> 11;
    int i = L >> 1;
    bool isW1 = ((L & 1) == 0);
    const float* W = (isW1 ? rw1 : rw2) + i * HID * HID;
    float sc = (isW1 && i > 0) ? 0.5f : 1.0f;     // fold wgt1 (ave_first)
    int n = t * 16 + (lane & 15);                  // output feature
    int k0 = kc * 32 + (lane >> 4) * 8;            // input feature base
    const float* src = W + n * HID + k0;           // W[n][k0..k0+7]
    int off = id * 8;
    for (int j = 0; j < 8; ++j) {
        float w = src[j] * sc;
        u32 b = __builtin_bit_cast(u32, w);
        u32 hb = b & 0xffff0000u;
        float lo = w - __builtin_bit_cast(float, hb);
        wsHi[off + j] = (unsigned short)(b >> 16);
        wsLo[off + j] = (unsigned short)(__builtin_bit_cast(u32, lo) >> 16);
    }
}

__global__ void __launch_bounds__(BT)
__attribute__((amdgpu_waves_per_eu(2, 2)))
siren_mfma(const float* __restrict__ x,
           const float* __restrict__ w0p, const float* __restrict__ b0p,
           const float* __restrict__ b1p, const float* __restrict__ b2p,
           const float* __restrict__ wfp, const float* __restrict__ bfp,
           const u4v* __restrict__ whi, const u4v* __restrict__ wlo,
           float* __restrict__ out, int NP)
{
    __shared__ float buf[4 * WAVE_LDS];            // 69632 B, wave-private staging

    const int tid = threadIdx.x;
    const int wv = tid >> 6, lane = tid & 63;
    const int ln = lane & 15, q = lane >> 4;
    const int q4 = q * 4;
    const int lnk = ln & 7;                        // LDS XOR-swizzle key (per row)
    const int rowbase0 = wv * WAVE_LDS + ln * WROW;        // mt0 row (point = ln)
    const int rowbase1 = rowbase0 + 16 * WROW;             // mt1 row (point = 16+ln)
    const int base_pt = blockIdx.x * 128 + wv * 32;

    // ---- first SineLayer, feature-major H
    LH64(DH)
    {
        int p0_ = base_pt + ln;      int i0_ = p0_ < NP ? p0_ : NP - 1;
        int p1_ = base_pt + 16 + ln; int i1_ = p1_ < NP ? p1_ : NP - 1;
        float X0 = x[3*i0_], Y0 = x[3*i0_+1], Z0 = x[3*i0_+2];
        float X1 = x[3*i1_], Y1 = x[3*i1_+1], Z1 = x[3*i1_+2];
        LNT8(F0)
    }

    // activation B-fragments (hi/lo) for 2 point-tiles x 4 k-chunks
    s8v FH00, FH01, FH02, FH03, FH10, FH11, FH12, FH13;
    s8v FL00, FL01, FL02, FL03, FL10, FL11, FL12, FL13;

    // ping-pong prefetch buffers
    u4v ga0, ga1, ga2, ga3, ra0, ra1, ra2, ra3;
    u4v gb0, gb1, gb2, gb3, rb0, rb1, rb2, rb3;
    f4v cva, cvb;

    for (int i = 0; i < NRES; ++i) {
        const int fb1 = (2*i) * 2048 + lane, fb2 = (2*i+1) * 2048 + lane;
        const float* __restrict__ B1l = b1p + i * HID;
        const float* __restrict__ B2l = b2p + i * HID;

        // prefetch mm1-t0 while the h transpose phase runs
        PF(a, fb1, B1l + q4)

        // h (D-layout) -> LDS -> B-fragments (swizzled b128 round-trip)
        LW16(WH)
        RS(0,0) RS(0,1) RS(0,2) RS(0,3)
        RS(1,0) RS(1,1) RS(1,2) RS(1,3)

        // ---- matmul1 -> s1, software-pipelined (prefetch t+1 before consume t)
        PF(b, fb1 + 256,  B1l + 16 + q4)   S1(0, a)
        PF(a, fb1 + 512,  B1l + 32 + q4)   S1(1, b)
        PF(b, fb1 + 768,  B1l + 48 + q4)   S1(2, a)
        PF(a, fb1 + 1024, B1l + 64 + q4)   S1(3, b)
        PF(b, fb1 + 1280, B1l + 80 + q4)   S1(4, a)
        PF(a, fb1 + 1536, B1l + 96 + q4)   S1(5, b)
        PF(b, fb1 + 1792, B1l + 112 + q4)  S1(6, a)
        PF(a, fb2,        B2l + q4)        S1(7, b)   // prefetch mm2-t0

        // s1 -> fragments (split-on-read)
        RS(0,0) RS(0,1) RS(0,2) RS(0,3)
        RS(1,0) RS(1,1) RS(1,2) RS(1,3)

        // ---- matmul2 -> s2; epilogue h += s2
        PF(b, fb2 + 256,  B2l + 16 + q4)   S2(0, a)
        PF(a, fb2 + 512,  B2l + 32 + q4)   S2(1, b)
        PF(b, fb2 + 768,  B2l + 48 + q4)   S2(2, a)
        PF(a, fb2 + 1024, B2l + 64 + q4)   S2(3, b)
        PF(b, fb2 + 1280, B2l + 80 + q4)   S2(4, a)
        PF(a, fb2 + 1536, B2l + 96 + q4)   S2(5, b)
        PF(b, fb2 + 1792, B2l + 112 + q4)  S2(6, a)
        S2(7, b)
    }

    // ---- final linear head
    float P0 = 0.f, P1 = 0.f;
    LNT8(HF)
    P0 += __shfl_xor(P0, 16); P0 += __shfl_xor(P0, 32);
    P1 += __shfl_xor(P1, 16); P1 += __shfl_xor(P1, 32);
    const float bf0 = bfp[0];
    if (q == 0) {
        int p0_ = base_pt + ln;
        if (p0_ < NP) out[p0_] = fmaf(P0, 0.5f, bf0);      // 0.5 = last-layer wgt2
        int p1_ = base_pt + 16 + ln;
        if (p1_ < NP) out[p1_] = fmaf(P1, 0.5f, bf0);
    }
}

extern "C" void kernel_launch(void* const* d_in, const int* in_sizes, int n_in,
                              void* d_out, int out_size, void* d_ws, size_t ws_size,
                              hipStream_t stream) {
    const float* x   = (const float*)d_in[0];
    const float* w0  = (const float*)d_in[1];
    const float* b0  = (const float*)d_in[2];
    const float* rw1 = (const float*)d_in[3];
    const float* rb1 = (const float*)d_in[4];
    const float* rw2 = (const float*)d_in[5];
    const float* rb2 = (const float*)d_in[6];
    const float* wf  = (const float*)d_in[7];
    const float* bf  = (const float*)d_in[8];
    float* out = (float*)d_out;

    unsigned short* wsHi = (unsigned short*)d_ws;          // needs 917504 B
    unsigned short* wsLo = wsHi + FRAG_ELEMS;

    const int n = in_sizes[0] / 3;                          // 200000
    prep_kernel<<<112, 256, 0, stream>>>(rw1, rw2, wsHi, wsLo);
    const int grid = (n + 127) / 128;
    siren_mfma<<<grid, BT, 0, stream>>>(x, w0, b0, rb1, rb2, wf, bf,
                                        (const u4v*)wsHi, (const u4v*)wsLo,
                                        out, n);
}